// Round 1
// baseline (272.404 us; speedup 1.0000x reference)
//
#include <hip/hip_runtime.h>
#include <math.h>

#define NT 512   // threads per block (8 waves); 512 blocks (one per channel h)

__device__ __forceinline__ float2 cmul(float2 a, float2 b) {
    return make_float2(a.x*b.x - a.y*b.y, a.x*b.y + a.y*b.x);
}

// Fully fused S4 layer, one block per channel h:
//  phase 0: per-channel params -> LDS (overlaid on upper half of buf)
//  phase 1: Cauchy kernel -> atRoots, written bit-reversed(12) into buf[0..4095]
//  phase 2: in-place DIT inverse FFT 4096 (unnormalized) -> K*4096 natural order
//  phase 3: pack z = u + i*K (K scaled 1/4096), zero-pad to 8192
//  phase 4: in-place DIF forward FFT 8192 (natural in -> bit-reversed out)
//  phase 5: unpack U,Kd from packed real-signal spectrum, Y = U*Kd (in brev order)
//  phase 6: in-place DIT inverse FFT 8192 -> y*8192 natural order
//  phase 7: out = Re(y)/8192 + D*u
__global__ void __launch_bounds__(NT, 4)
s4_fused(const float* __restrict__ u,
         const float* __restrict__ Lre, const float* __restrict__ Lim,
         const float* __restrict__ Pre, const float* __restrict__ Pim,
         const float* __restrict__ Bre, const float* __restrict__ Bim,
         const float* __restrict__ Cin, const float* __restrict__ Din,
         const float* __restrict__ logstep,
         float* __restrict__ out)
{
    __shared__ float2 buf[8192];   // 64 KB -> 2 blocks/CU
    const int tid = threadIdx.x;
    const int h = blockIdx.x;

    // ---- phase 0: params in upper LDS (dead after phase 1; phase 3 overwrites) ----
    float2* par = buf + 4096;  // [0..63]=Lam, [64..]=w00, [128..]=w01, [192..]=w10, [256..]=w11
    if (tid < 64) {
        const int n = tid;
        float lre = fminf(Lre[h*64 + n], -1e-4f);
        float lim = Lim[h*64 + n];
        par[n] = make_float2(lre, lim);
        float pr = Pre[h*64 + n], pi = Pim[h*64 + n];
        float br = Bre[h*64 + n], bi = Bim[h*64 + n];
        float cr = Cin[h*128 + 2*n], ci = Cin[h*128 + 2*n + 1];
        float2 cc = make_float2(cr, -ci);   // conj(C)
        float2 pc = make_float2(pr, -pi);   // conj(P)
        par[ 64 + n] = cmul(cc, make_float2(br, bi));
        par[128 + n] = cmul(cc, make_float2(pr, pi));
        par[192 + n] = cmul(pc, make_float2(br, bi));
        par[256 + n] = cmul(pc, make_float2(pr, pi));
    }
    __syncthreads();

    const float step = expf(logstep[h]);
    const float tos  = 2.0f / step;

    // ---- phase 1: Cauchy kernel (two half-passes of 4 l's to bound VGPRs) ----
    for (int hp = 0; hp < 2; ++hp) {
        float2 g[4], cf[4], k00[4], k01[4], k10[4], k11[4];
        const int lbase = hp * (4*NT);
        #pragma unroll
        for (int i = 0; i < 4; ++i) {
            int l = lbase + i*NT + tid;
            // mimic the reference's f32 angle: -2pi_f32 * (l/4096); sin/cos rounded from double
            float ang = -6.2831855f * ((float)l * (1.0f/4096.0f));
            double ds, dc;
            sincos((double)ang, &ds, &dc);
            float2 Om  = make_float2((float)dc, (float)ds);
            float2 num = make_float2(1.0f - Om.x, -Om.y);
            float2 den = make_float2(1.0f + Om.x,  Om.y);
            float dinv = 1.0f / (den.x*den.x + den.y*den.y);
            g[i]  = make_float2(tos * ((num.x*den.x + num.y*den.y) * dinv),
                                tos * ((num.y*den.x - num.x*den.y) * dinv));
            cf[i] = make_float2(2.0f*den.x*dinv, -2.0f*den.y*dinv);   // c = 2/(1+Om)
            k00[i] = make_float2(0,0); k01[i] = make_float2(0,0);
            k10[i] = make_float2(0,0); k11[i] = make_float2(0,0);
        }
        for (int n = 0; n < 64; ++n) {
            float2 lam = par[n];
            float2 w00 = par[64+n], w01 = par[128+n], w10 = par[192+n], w11 = par[256+n];
            #pragma unroll
            for (int i = 0; i < 4; ++i) {
                float dr = g[i].x - lam.x;
                float di = g[i].y - lam.y;
                float inv = 1.0f / (dr*dr + di*di);
                float er = dr*inv, ei = -di*inv;   // 1/(g - Lam)
                k00[i].x += w00.x*er - w00.y*ei; k00[i].y += w00.x*ei + w00.y*er;
                k01[i].x += w01.x*er - w01.y*ei; k01[i].y += w01.x*ei + w01.y*er;
                k10[i].x += w10.x*er - w10.y*ei; k10[i].y += w10.x*ei + w10.y*er;
                k11[i].x += w11.x*er - w11.y*ei; k11[i].y += w11.x*ei + w11.y*er;
            }
        }
        #pragma unroll
        for (int i = 0; i < 4; ++i) {
            int l = lbase + i*NT + tid;
            float2 opk = make_float2(1.0f + k11[i].x, k11[i].y);
            float iv = 1.0f / (opk.x*opk.x + opk.y*opk.y);
            float2 r11 = make_float2(opk.x*iv, -opk.y*iv);       // 1/(1+k11)
            float2 t  = cmul(cmul(k01[i], r11), k10[i]);
            float2 ar = make_float2(k00[i].x - t.x, k00[i].y - t.y);
            float2 res = cmul(cf[i], ar);                         // atRoots[l]
            buf[(int)(__builtin_bitreverse32((unsigned)l) >> 20)] = res;
        }
    }
    __syncthreads();

    // ---- phase 2: inverse FFT 4096 (DIT, brev input -> natural), unnormalized ----
    for (int m = 2; m <= 4096; m <<= 1) {
        const int half = m >> 1;
        const float fm = 6.2831853f / (float)m;   // sign = +1 (inverse)
        #pragma unroll
        for (int i = 0; i < 4; ++i) {
            int b = i*NT + tid;          // 2048 butterflies
            int j = b & (half - 1);
            int i0 = 2*b - j;
            int i1 = i0 + half;
            float sw, cw;
            __sincosf((float)j * fm, &sw, &cw);
            float2 a = buf[i0];
            float2 t = cmul(make_float2(cw, sw), buf[i1]);
            buf[i0] = make_float2(a.x + t.x, a.y + t.y);
            buf[i1] = make_float2(a.x - t.x, a.y - t.y);
        }
        __syncthreads();
    }

    // ---- phase 3: pack z = u + i*K, zero-pad ----
    float uval[8];
    {
        float kval[8];
        #pragma unroll
        for (int i = 0; i < 8; ++i) {
            int l = i*NT + tid;
            kval[i] = buf[l].x * (1.0f/4096.0f);   // K = Re(ifft)/4096
            uval[i] = u[h*4096 + l];
        }
        __syncthreads();
        #pragma unroll
        for (int i = 0; i < 8; ++i) {
            int l = i*NT + tid;
            buf[l]        = make_float2(uval[i], kval[i]);
            buf[l + 4096] = make_float2(0.0f, 0.0f);
        }
    }
    __syncthreads();

    // ---- phase 4: forward FFT 8192 (DIF, natural -> bit-reversed) ----
    for (int m = 8192; m >= 2; m >>= 1) {
        const int half = m >> 1;
        const float fm = -6.2831853f / (float)m;  // sign = -1 (forward)
        #pragma unroll
        for (int i = 0; i < 8; ++i) {
            int b = i*NT + tid;          // 4096 butterflies
            int j = b & (half - 1);
            int i0 = 2*b - j;
            int i1 = i0 + half;
            float2 a = buf[i0], c = buf[i1];
            buf[i0] = make_float2(a.x + c.x, a.y + c.y);
            float sw, cw;
            __sincosf((float)j * fm, &sw, &cw);
            buf[i1] = cmul(make_float2(cw, sw), make_float2(a.x - c.x, a.y - c.y));
        }
        __syncthreads();
    }

    // ---- phase 5: unpack packed-real spectra, multiply (in brev-13 addressing) ----
    // Z[k] sits at brev13(k). U = (Z[k]+conj(Z[-k]))/2, Kd = (Z[k]-conj(Z[-k]))/(2i).
    // Each k<=4096 task owns both brev13(k) and brev13(8192-k): no races.
    #pragma unroll
    for (int i = 0; i < 9; ++i) {
        int k = i*NT + tid;
        if (k <= 4096) {
            int a1 = (int)(__builtin_bitreverse32((unsigned)k) >> 19);
            int a2 = (int)(__builtin_bitreverse32((unsigned)((8192 - k) & 8191)) >> 19);
            float2 z1 = buf[a1], z2 = buf[a2];
            float2 U  = make_float2(0.5f*(z1.x + z2.x), 0.5f*(z1.y - z2.y));
            float2 V  = make_float2(z1.x - z2.x, z1.y + z2.y);   // Z - conj(Z[-k])
            float2 Kd = make_float2(0.5f*V.y, -0.5f*V.x);        // V * (-i/2)
            float2 Y  = cmul(U, Kd);
            buf[a1] = Y;
            buf[a2] = make_float2(Y.x, -Y.y);
        }
    }
    __syncthreads();

    // ---- phase 6: inverse FFT 8192 (DIT, brev input -> natural), unnormalized ----
    for (int m = 2; m <= 8192; m <<= 1) {
        const int half = m >> 1;
        const float fm = 6.2831853f / (float)m;
        #pragma unroll
        for (int i = 0; i < 8; ++i) {
            int b = i*NT + tid;
            int j = b & (half - 1);
            int i0 = 2*b - j;
            int i1 = i0 + half;
            float sw, cw;
            __sincosf((float)j * fm, &sw, &cw);
            float2 a = buf[i0];
            float2 t = cmul(make_float2(cw, sw), buf[i1]);
            buf[i0] = make_float2(a.x + t.x, a.y + t.y);
            buf[i1] = make_float2(a.x - t.x, a.y - t.y);
        }
        __syncthreads();
    }

    // ---- phase 7: epilogue ----
    const float Dh = Din[h];
    const float scale = 1.0f / 8192.0f;
    #pragma unroll
    for (int i = 0; i < 8; ++i) {
        int l = i*NT + tid;
        out[h*4096 + l] = buf[l].x * scale + Dh * uval[i];
    }
}

extern "C" void kernel_launch(void* const* d_in, const int* in_sizes, int n_in,
                              void* d_out, int out_size, void* d_ws, size_t ws_size,
                              hipStream_t stream)
{
    const float* u       = (const float*)d_in[0];
    const float* Lre     = (const float*)d_in[1];
    const float* Lim     = (const float*)d_in[2];
    const float* Pre     = (const float*)d_in[3];
    const float* Pim     = (const float*)d_in[4];
    const float* Bre     = (const float*)d_in[5];
    const float* Bim     = (const float*)d_in[6];
    const float* Cin     = (const float*)d_in[7];
    const float* Din     = (const float*)d_in[8];
    const float* logstep = (const float*)d_in[9];
    float* out = (float*)d_out;
    const int H = in_sizes[8];  // D is [H,1]
    hipLaunchKernelGGL(s4_fused, dim3(H), dim3(NT), 0, stream,
                       u, Lre, Lim, Pre, Pim, Bre, Bim, Cin, Din, logstep, out);
}

// Round 2
// 217.254 us; speedup vs baseline: 1.2538x; 1.2538x over previous
//
#include <hip/hip_runtime.h>
#include <math.h>

#define NT 512   // threads per block; 512 blocks (one per channel h)

__device__ __forceinline__ float2 cmul(float2 a, float2 b) {
    return make_float2(a.x*b.x - a.y*b.y, a.x*b.y + a.y*b.x);
}
__device__ __forceinline__ float2 cadd(float2 a, float2 b){ return make_float2(a.x+b.x, a.y+b.y); }
__device__ __forceinline__ float2 csub(float2 a, float2 b){ return make_float2(a.x-b.x, a.y-b.y); }

// XOR bank swizzle: float2 elements -> bank = (2e)%32 depends on e mod 16.
// Fold bits 5-8 and 9-12 into low 4 bits; bijective, zero extra LDS.
__device__ __forceinline__ int SW(int e){ return e ^ (((e>>5) ^ (e>>9)) & 15); }

// base-4 digit reversal of a 12-bit index
__device__ __forceinline__ int d4r6(int x){
    int r = (int)(__builtin_bitreverse32((unsigned)x) >> 20);      // bit-reverse 12 bits
    return ((r & 0x555) << 1) | ((r >> 1) & 0x555);                // fix bit order inside digits
}

// ---- radix-4 DIT stage, inverse (sigma=+1). In-place on buf (swizzled addressing).
// NB butterflies per thread; q = sub-transform size; twiddle W_{4q}^{j}, j = b mod q.
template<int NB>
__device__ __forceinline__ void r4_dit_inv(float2* buf, int tid, int q) {
    const float fm = 6.2831853072f / (float)(4*q);
    int j0 = tid & (q-1);
    float sb, cb; __sincosf(fm*(float)j0, &sb, &cb);
    float2 W1a = make_float2(cb, sb), W1b = W1a;
    if (q == 1024) { float ss, cs; __sincosf(fm*512.0f, &ss, &cs); W1b = cmul(W1a, make_float2(cs, ss)); }
    float2 W2a = cmul(W1a,W1a), W3a = cmul(W2a,W1a);
    float2 W2b = cmul(W1b,W1b), W3b = cmul(W2b,W1b);
    #pragma unroll
    for (int i = 0; i < NB; ++i) {
        int b = i*NT + tid;
        int j = b & (q-1);
        int e0 = 4*b - 3*j;           // block base + j
        int a0 = SW(e0), a1 = SW(e0+q), a2 = SW(e0+2*q), a3 = SW(e0+3*q);
        float2 x0 = buf[a0], x1 = buf[a1], x2 = buf[a2], x3 = buf[a3];
        float2 W1 = (i&1)?W1b:W1a, W2 = (i&1)?W2b:W2a, W3 = (i&1)?W3b:W3a;
        float2 t1 = cmul(x1,W1), t2 = cmul(x2,W2), t3 = cmul(x3,W3);
        float2 E0 = cadd(x0,t2), E1 = cadd(t1,t3);
        float2 O0 = csub(x0,t2), O1 = csub(t1,t3);
        buf[a0] = cadd(E0,E1);
        buf[a2] = csub(E0,E1);
        buf[a1] = make_float2(O0.x - O1.y, O0.y + O1.x);   // O0 + i*O1
        buf[a3] = make_float2(O0.x + O1.y, O0.y - O1.x);   // O0 - i*O1
    }
    __syncthreads();
}

// ---- radix-4 DIF stage, forward (sigma=-1): butterfly then twiddle.
template<int NB>
__device__ __forceinline__ void r4_dif_fwd(float2* buf, int tid, int q) {
    const float fm = -6.2831853072f / (float)(4*q);
    int j0 = tid & (q-1);
    float sb, cb; __sincosf(fm*(float)j0, &sb, &cb);
    float2 W1a = make_float2(cb, sb), W1b = W1a;
    if (q == 1024) { float ss, cs; __sincosf(fm*512.0f, &ss, &cs); W1b = cmul(W1a, make_float2(cs, ss)); }
    float2 W2a = cmul(W1a,W1a), W3a = cmul(W2a,W1a);
    float2 W2b = cmul(W1b,W1b), W3b = cmul(W2b,W1b);
    #pragma unroll
    for (int i = 0; i < NB; ++i) {
        int b = i*NT + tid;
        int j = b & (q-1);
        int e0 = 4*b - 3*j;
        int a0 = SW(e0), a1 = SW(e0+q), a2 = SW(e0+2*q), a3 = SW(e0+3*q);
        float2 x0 = buf[a0], x1 = buf[a1], x2 = buf[a2], x3 = buf[a3];
        float2 W1 = (i&1)?W1b:W1a, W2 = (i&1)?W2b:W2a, W3 = (i&1)?W3b:W3a;
        float2 E0 = cadd(x0,x2), E1 = cadd(x1,x3);
        float2 O0 = csub(x0,x2), O1 = csub(x1,x3);
        buf[a0] = cadd(E0,E1);
        float2 z2 = csub(E0,E1);
        float2 z1 = make_float2(O0.x + O1.y, O0.y - O1.x);  // O0 - i*O1
        float2 z3 = make_float2(O0.x - O1.y, O0.y + O1.x);  // O0 + i*O1
        buf[a1] = cmul(z1, W1);
        buf[a2] = cmul(z2, W2);
        buf[a3] = cmul(z3, W3);
    }
    __syncthreads();
}

// Fused S4 layer, one block per channel h.
//  P1: Cauchy -> atRoots scattered at d4r6(l)         (lower 4096)
//  P2: radix-4 DIT ifft4096 -> K*4096 natural
//  P3: pack z = u + i*K/4096, zero upper half
//  P4: forward fft8192: r2 DIF (m=8192) + 6 radix-4 DIF stages -> freq k at (k&1)*4096 + d4r6(k>>1)
//  P5: unpack U,Kd; Y=U*Kd; half-size-inverse pack v[r] = (Y[r]+Y[r+4096]) + i W^r (Y[r]-Y[r+4096]),
//      scattered at d4r6(r)
//  P6: radix-4 DIT ifft4096 -> p[n] = y[2n] + i*y[2n+1] (unnormalized, /8192)
//  P7: out[2n],out[2n+1] = p/8192 + D*u   (float2 stores)
__global__ void __launch_bounds__(NT, 4)
s4_fused(const float* __restrict__ u,
         const float* __restrict__ Lre, const float* __restrict__ Lim,
         const float* __restrict__ Pre, const float* __restrict__ Pim,
         const float* __restrict__ Bre, const float* __restrict__ Bim,
         const float* __restrict__ Cin, const float* __restrict__ Din,
         const float* __restrict__ logstep,
         float* __restrict__ out)
{
    __shared__ float2 buf[8192];   // 64 KB -> 2 blocks/CU
    const int tid = threadIdx.x;
    const int h = blockIdx.x;

    // ---- P0: params in upper half (raw addressing; dead after P1) ----
    float2* par = buf + 4096;      // [0..63]=Lam, +64=w00, +128=w01, +192=w10, +256=w11(real)
    if (tid < 64) {
        const int n = tid;
        float lre = fminf(Lre[h*64+n], -1e-4f);
        float lim = Lim[h*64+n];
        par[n] = make_float2(lre, lim);
        float pr = Pre[h*64+n], pi = Pim[h*64+n];
        float br = Bre[h*64+n], bi = Bim[h*64+n];
        float cr = Cin[h*128+2*n], ci = Cin[h*128+2*n+1];
        float2 cc = make_float2(cr, -ci);              // conj(C)
        par[64+n]  = cmul(cc, make_float2(br, bi));    // w00 = conj(C)*B
        par[128+n] = cmul(cc, make_float2(pr, pi));    // w01 = conj(C)*P
        float2 pc = make_float2(pr, -pi);              // conj(P)
        par[192+n] = cmul(pc, make_float2(br, bi));    // w10 = conj(P)*B
        par[256+n] = make_float2(pr*pr + pi*pi, 0.0f); // w11 = |P|^2 (real!)
    }
    __syncthreads();

    const float step = expf(logstep[h]);
    const float tos  = 2.0f / step;

    // ---- P1: Cauchy kernel (two half-passes of 4 l's) ----
    for (int hp = 0; hp < 2; ++hp) {
        float2 g[4], cf[4], k00[4], k01[4], k10[4], k11[4];
        const int lbase = hp*(4*NT);
        #pragma unroll
        for (int i = 0; i < 4; ++i) {
            int l = lbase + i*NT + tid;
            // mimic reference's f32 angle; sin/cos rounded from double (critical near l=2048)
            float ang = -6.2831855f * ((float)l * (1.0f/4096.0f));
            double ds, dc;
            sincos((double)ang, &ds, &dc);
            float2 Om  = make_float2((float)dc, (float)ds);
            float2 num = make_float2(1.0f-Om.x, -Om.y);
            float2 den = make_float2(1.0f+Om.x,  Om.y);
            float dinv = 1.0f/(den.x*den.x + den.y*den.y);
            g[i]  = make_float2(tos*((num.x*den.x+num.y*den.y)*dinv),
                                tos*((num.y*den.x-num.x*den.y)*dinv));
            cf[i] = make_float2(2.0f*den.x*dinv, -2.0f*den.y*dinv);
            k00[i]=make_float2(0,0); k01[i]=make_float2(0,0);
            k10[i]=make_float2(0,0); k11[i]=make_float2(0,0);
        }
        for (int n = 0; n < 64; ++n) {
            float2 lam = par[n];
            float2 w00 = par[64+n], w01 = par[128+n], w10 = par[192+n];
            float  w11r = par[256+n].x;
            #pragma unroll
            for (int i = 0; i < 4; ++i) {
                float dr = g[i].x - lam.x;
                float di = g[i].y - lam.y;
                float inv = __builtin_amdgcn_rcpf(dr*dr + di*di);  // ~1ulp, plenty for thr
                float er = dr*inv, ei = -di*inv;                   // 1/(g - Lam)
                k00[i].x += w00.x*er - w00.y*ei; k00[i].y += w00.x*ei + w00.y*er;
                k01[i].x += w01.x*er - w01.y*ei; k01[i].y += w01.x*ei + w01.y*er;
                k10[i].x += w10.x*er - w10.y*ei; k10[i].y += w10.x*ei + w10.y*er;
                k11[i].x += w11r*er;             k11[i].y += w11r*ei;
            }
        }
        #pragma unroll
        for (int i = 0; i < 4; ++i) {
            int l = lbase + i*NT + tid;
            float2 opk = make_float2(1.0f + k11[i].x, k11[i].y);
            float iv = 1.0f/(opk.x*opk.x + opk.y*opk.y);
            float2 r11 = make_float2(opk.x*iv, -opk.y*iv);
            float2 t  = cmul(cmul(k01[i], r11), k10[i]);
            float2 ar = make_float2(k00[i].x - t.x, k00[i].y - t.y);
            buf[SW(d4r6(l))] = cmul(cf[i], ar);       // scatter for radix-4 DIT
        }
    }
    __syncthreads();

    // ---- P2: ifft4096 (6 radix-4 DIT stages) -> K*4096 natural ----
    #pragma unroll
    for (int q = 1; q <= 1024; q *= 4) r4_dit_inv<2>(buf, tid, q);

    // ---- P3: pack z = u + i*K, zero-pad ----
    {
        float kv[8], uval[8];
        #pragma unroll
        for (int i = 0; i < 8; ++i) {
            int l = i*NT + tid;
            kv[i]   = buf[SW(l)].x * (1.0f/4096.0f);
            uval[i] = u[h*4096 + l];
        }
        __syncthreads();
        #pragma unroll
        for (int i = 0; i < 8; ++i) {
            int l = i*NT + tid;
            buf[SW(l)]        = make_float2(uval[i], kv[i]);
            buf[SW(l+4096)]   = make_float2(0.0f, 0.0f);
        }
    }
    __syncthreads();

    // ---- P4: forward fft8192 = r2 DIF (m=8192) + 6 radix-4 DIF stages per half ----
    {
        const float fm = -6.2831853072f / 8192.0f;
        float sb, cb; __sincosf(fm*(float)tid, &sb, &cb);
        float ss, cs; __sincosf(fm*512.0f, &ss, &cs);
        float2 cur = make_float2(cb, sb);
        const float2 stp = make_float2(cs, ss);
        #pragma unroll
        for (int i = 0; i < 8; ++i) {
            int j = i*NT + tid;
            int a0 = SW(j), a1 = SW(j+4096);
            float2 a = buf[a0], c = buf[a1];
            buf[a0] = cadd(a,c);
            buf[a1] = cmul(csub(a,c), cur);   // * W_8192^{-j}
            cur = cmul(cur, stp);
        }
        __syncthreads();
    }
    #pragma unroll
    for (int q = 1024; q >= 1; q >>= 2) r4_dif_fwd<4>(buf, tid, q);

    // ---- P5: unpack + multiply + half-size-inverse pack ----
    // Z[k] lives at (k&1)*4096 + d4r6(k>>1).
    {
        const float fm = 6.2831853072f / 8192.0f;   // W = e^{+2pi i/8192}
        float sb, cb; __sincosf(fm*(float)tid, &sb, &cb);
        float ss, cs; __sincosf(fm*512.0f, &ss, &cs);
        float2 cur = make_float2(cb, sb);
        const float2 stp = make_float2(cs, ss);
        float2 v[8];
        #pragma unroll
        for (int i = 0; i < 8; ++i) {
            int r  = i*NT + tid;                   // 0..4095
            int k1 = r,        k1c = (8192 - r) & 8191;
            int k2 = r + 4096, k2c = 4096 - r;
            float2 za = buf[SW(((k1 &1)<<12) + d4r6(k1 >>1))];
            float2 zb = buf[SW(((k1c&1)<<12) + d4r6(k1c>>1))];
            float2 zc = buf[SW(((k2 &1)<<12) + d4r6(k2 >>1))];
            float2 zd = buf[SW(((k2c&1)<<12) + d4r6(k2c>>1))];
            // Y(k) from (Z[k], Z[-k]):  U = (Z+conj(Z-))/2, Kd = (Z-conj(Z-))*(-i/2), Y = U*Kd
            float2 U1 = make_float2(0.5f*(za.x+zb.x), 0.5f*(za.y-zb.y));
            float2 V1 = make_float2(za.x-zb.x, za.y+zb.y);
            float2 K1 = make_float2(0.5f*V1.y, -0.5f*V1.x);
            float2 Yr = cmul(U1, K1);                               // Y[r]
            float2 U2 = make_float2(0.5f*(zc.x+zd.x), 0.5f*(zc.y-zd.y));
            float2 V2 = make_float2(zc.x-zd.x, zc.y+zd.y);
            float2 K2 = make_float2(0.5f*V2.y, -0.5f*V2.x);
            float2 Ys = cmul(U2, K2);                               // Y[r+4096]
            float2 A  = cadd(Yr, Ys);
            float2 Bv = cmul(cur, csub(Yr, Ys));
            v[i] = make_float2(A.x - Bv.y, A.y + Bv.x);             // A + i*W^r*(Yr-Ys)
            cur = cmul(cur, stp);
        }
        __syncthreads();   // all reads done before any scatter write
        #pragma unroll
        for (int i = 0; i < 8; ++i) {
            int r = i*NT + tid;
            buf[SW(d4r6(r))] = v[i];
        }
        __syncthreads();
    }

    // ---- P6: ifft4096 (6 radix-4 DIT stages) -> p[n] = y[2n] + i*y[2n+1] ----
    #pragma unroll
    for (int q = 1; q <= 1024; q *= 4) r4_dit_inv<2>(buf, tid, q);

    // ---- P7: epilogue, float2 stores ----
    {
        const float Dh = Din[h];
        const float sc = 1.0f / 8192.0f;
        const float2* u2   = (const float2*)(u + h*4096);
        float2*       out2 = (float2*)(out + h*4096);
        #pragma unroll
        for (int i = 0; i < 4; ++i) {
            int n = i*NT + tid;                   // 0..2047 -> outputs 2n, 2n+1
            float2 p  = buf[SW(n)];
            float2 uu = u2[n];
            out2[n] = make_float2(p.x*sc + Dh*uu.x, p.y*sc + Dh*uu.y);
        }
    }
}

extern "C" void kernel_launch(void* const* d_in, const int* in_sizes, int n_in,
                              void* d_out, int out_size, void* d_ws, size_t ws_size,
                              hipStream_t stream)
{
    const float* u       = (const float*)d_in[0];
    const float* Lre     = (const float*)d_in[1];
    const float* Lim     = (const float*)d_in[2];
    const float* Pre     = (const float*)d_in[3];
    const float* Pim     = (const float*)d_in[4];
    const float* Bre     = (const float*)d_in[5];
    const float* Bim     = (const float*)d_in[6];
    const float* Cin     = (const float*)d_in[7];
    const float* Din     = (const float*)d_in[8];
    const float* logstep = (const float*)d_in[9];
    float* out = (float*)d_out;
    const int H = in_sizes[8];  // D is [H,1]
    hipLaunchKernelGGL(s4_fused, dim3(H), dim3(NT), 0, stream,
                       u, Lre, Lim, Pre, Pim, Bre, Bim, Cin, Din, logstep, out);
}

// Round 3
// 216.335 us; speedup vs baseline: 1.2592x; 1.0042x over previous
//
#include <hip/hip_runtime.h>
#include <math.h>

#define NT 512   // threads per block; 512 blocks (one per channel h)

__device__ __forceinline__ float2 cmul(float2 a, float2 b) {
    return make_float2(a.x*b.x - a.y*b.y, a.x*b.y + a.y*b.x);
}
__device__ __forceinline__ float2 cadd(float2 a, float2 b){ return make_float2(a.x+b.x, a.y+b.y); }
__device__ __forceinline__ float2 csub(float2 a, float2 b){ return make_float2(a.x-b.x, a.y-b.y); }

// XOR bank swizzle: float2 elements -> bank = (2e)%32 depends on e mod 16.
// Fold bits 5-8 and 9-12 into low 4 bits; bijective, zero extra LDS.
__device__ __forceinline__ int SW(int e){ return e ^ (((e>>5) ^ (e>>9)) & 15); }

// base-4 digit reversal of a 12-bit index
__device__ __forceinline__ int d4r6(int x){
    int r = (int)(__builtin_bitreverse32((unsigned)x) >> 20);      // bit-reverse 12 bits
    return ((r & 0x555) << 1) | ((r >> 1) & 0x555);                // fix bit order inside digits
}

// ---- radix-4 DIT stage, inverse (sigma=+1). In-place on buf (swizzled addressing).
template<int NB>
__device__ __forceinline__ void r4_dit_inv(float2* buf, int tid, int q) {
    const float fm = 6.2831853072f / (float)(4*q);
    int j0 = tid & (q-1);
    float sb, cb; __sincosf(fm*(float)j0, &sb, &cb);
    float2 W1a = make_float2(cb, sb), W1b = W1a;
    if (q == 1024) { float ss, cs; __sincosf(fm*512.0f, &ss, &cs); W1b = cmul(W1a, make_float2(cs, ss)); }
    float2 W2a = cmul(W1a,W1a), W3a = cmul(W2a,W1a);
    float2 W2b = cmul(W1b,W1b), W3b = cmul(W2b,W1b);
    #pragma unroll
    for (int i = 0; i < NB; ++i) {
        int b = i*NT + tid;
        int j = b & (q-1);
        int e0 = 4*b - 3*j;           // block base + j
        int a0 = SW(e0), a1 = SW(e0+q), a2 = SW(e0+2*q), a3 = SW(e0+3*q);
        float2 x0 = buf[a0], x1 = buf[a1], x2 = buf[a2], x3 = buf[a3];
        float2 W1 = (i&1)?W1b:W1a, W2 = (i&1)?W2b:W2a, W3 = (i&1)?W3b:W3a;
        float2 t1 = cmul(x1,W1), t2 = cmul(x2,W2), t3 = cmul(x3,W3);
        float2 E0 = cadd(x0,t2), E1 = cadd(t1,t3);
        float2 O0 = csub(x0,t2), O1 = csub(t1,t3);
        buf[a0] = cadd(E0,E1);
        buf[a2] = csub(E0,E1);
        buf[a1] = make_float2(O0.x - O1.y, O0.y + O1.x);   // O0 + i*O1
        buf[a3] = make_float2(O0.x + O1.y, O0.y - O1.x);   // O0 - i*O1
    }
    __syncthreads();
}

// ---- radix-4 DIF stage, forward (sigma=-1): butterfly then twiddle.
template<int NB>
__device__ __forceinline__ void r4_dif_fwd(float2* buf, int tid, int q) {
    const float fm = -6.2831853072f / (float)(4*q);
    int j0 = tid & (q-1);
    float sb, cb; __sincosf(fm*(float)j0, &sb, &cb);
    float2 W1a = make_float2(cb, sb), W1b = W1a;
    if (q == 1024) { float ss, cs; __sincosf(fm*512.0f, &ss, &cs); W1b = cmul(W1a, make_float2(cs, ss)); }
    float2 W2a = cmul(W1a,W1a), W3a = cmul(W2a,W1a);
    float2 W2b = cmul(W1b,W1b), W3b = cmul(W2b,W1b);
    #pragma unroll
    for (int i = 0; i < NB; ++i) {
        int b = i*NT + tid;
        int j = b & (q-1);
        int e0 = 4*b - 3*j;
        int a0 = SW(e0), a1 = SW(e0+q), a2 = SW(e0+2*q), a3 = SW(e0+3*q);
        float2 x0 = buf[a0], x1 = buf[a1], x2 = buf[a2], x3 = buf[a3];
        float2 W1 = (i&1)?W1b:W1a, W2 = (i&1)?W2b:W2a, W3 = (i&1)?W3b:W3a;
        float2 E0 = cadd(x0,x2), E1 = cadd(x1,x3);
        float2 O0 = csub(x0,x2), O1 = csub(x1,x3);
        buf[a0] = cadd(E0,E1);
        float2 z2 = csub(E0,E1);
        float2 z1 = make_float2(O0.x + O1.y, O0.y - O1.x);  // O0 - i*O1
        float2 z3 = make_float2(O0.x - O1.y, O0.y + O1.x);  // O0 + i*O1
        buf[a1] = cmul(z1, W1);
        buf[a2] = cmul(z2, W2);
        buf[a3] = cmul(z3, W3);
    }
    __syncthreads();
}

// Fused S4 layer, one block per channel h. Phases as in R1.
// __launch_bounds__(NT,2): VGPR cap 1024. LDS (64KB) caps occupancy at 2 blocks/CU
// = 4 waves/EU anyway; VGPR only binds above ~512 regs, so give the allocator room
// (R1 at the default budget spilled ~145MB/dispatch to scratch -> HBM-bound).
__global__ void __launch_bounds__(NT, 2)
s4_fused(const float* __restrict__ u,
         const float* __restrict__ Lre, const float* __restrict__ Lim,
         const float* __restrict__ Pre, const float* __restrict__ Pim,
         const float* __restrict__ Bre, const float* __restrict__ Bim,
         const float* __restrict__ Cin, const float* __restrict__ Din,
         const float* __restrict__ logstep,
         float* __restrict__ out)
{
    __shared__ float2 buf[8192];   // 64 KB -> 2 blocks/CU
    const int tid = threadIdx.x;
    const int h = blockIdx.x;

    // ---- P0: params in upper half (raw addressing; dead after P1) ----
    float2* par = buf + 4096;      // [0..63]=Lam, +64=w00, +128=w01, +192=w10, +256=w11(real)
    if (tid < 64) {
        const int n = tid;
        float lre = fminf(Lre[h*64+n], -1e-4f);
        float lim = Lim[h*64+n];
        par[n] = make_float2(lre, lim);
        float pr = Pre[h*64+n], pi = Pim[h*64+n];
        float br = Bre[h*64+n], bi = Bim[h*64+n];
        float cr = Cin[h*128+2*n], ci = Cin[h*128+2*n+1];
        float2 cc = make_float2(cr, -ci);              // conj(C)
        par[64+n]  = cmul(cc, make_float2(br, bi));    // w00 = conj(C)*B
        par[128+n] = cmul(cc, make_float2(pr, pi));    // w01 = conj(C)*P
        float2 pc = make_float2(pr, -pi);              // conj(P)
        par[192+n] = cmul(pc, make_float2(br, bi));    // w10 = conj(P)*B
        par[256+n] = make_float2(pr*pr + pi*pi, 0.0f); // w11 = |P|^2 (real!)
    }
    __syncthreads();

    const float step = expf(logstep[h]);
    const float tos  = 2.0f / step;

    // ---- P1: Cauchy kernel (two half-passes of 4 l's; keep halves separate to
    //      bound live accumulator state at 4x4 float2) ----
    #pragma unroll 1
    for (int hp = 0; hp < 2; ++hp) {
        float2 g[4], cf[4], k00[4], k01[4], k10[4], k11[4];
        const int lbase = hp*(4*NT);
        #pragma unroll
        for (int i = 0; i < 4; ++i) {
            int l = lbase + i*NT + tid;
            // mimic reference's f32 angle; sin/cos rounded from double (critical near l=2048)
            float ang = -6.2831855f * ((float)l * (1.0f/4096.0f));
            double ds, dc;
            sincos((double)ang, &ds, &dc);
            float2 Om  = make_float2((float)dc, (float)ds);
            float2 num = make_float2(1.0f-Om.x, -Om.y);
            float2 den = make_float2(1.0f+Om.x,  Om.y);
            float dinv = 1.0f/(den.x*den.x + den.y*den.y);
            g[i]  = make_float2(tos*((num.x*den.x+num.y*den.y)*dinv),
                                tos*((num.y*den.x-num.x*den.y)*dinv));
            cf[i] = make_float2(2.0f*den.x*dinv, -2.0f*den.y*dinv);
            k00[i]=make_float2(0,0); k01[i]=make_float2(0,0);
            k10[i]=make_float2(0,0); k11[i]=make_float2(0,0);
        }
        #pragma unroll 1
        for (int n = 0; n < 64; ++n) {
            float2 lam = par[n];
            float2 w00 = par[64+n], w01 = par[128+n], w10 = par[192+n];
            float  w11r = par[256+n].x;
            #pragma unroll
            for (int i = 0; i < 4; ++i) {
                float dr = g[i].x - lam.x;
                float di = g[i].y - lam.y;
                float inv = __builtin_amdgcn_rcpf(dr*dr + di*di);
                float er = dr*inv, ei = -di*inv;                   // 1/(g - Lam)
                k00[i].x += w00.x*er - w00.y*ei; k00[i].y += w00.x*ei + w00.y*er;
                k01[i].x += w01.x*er - w01.y*ei; k01[i].y += w01.x*ei + w01.y*er;
                k10[i].x += w10.x*er - w10.y*ei; k10[i].y += w10.x*ei + w10.y*er;
                k11[i].x += w11r*er;             k11[i].y += w11r*ei;
            }
        }
        #pragma unroll
        for (int i = 0; i < 4; ++i) {
            int l = lbase + i*NT + tid;
            float2 opk = make_float2(1.0f + k11[i].x, k11[i].y);
            float iv = 1.0f/(opk.x*opk.x + opk.y*opk.y);
            float2 r11 = make_float2(opk.x*iv, -opk.y*iv);
            float2 t  = cmul(cmul(k01[i], r11), k10[i]);
            float2 ar = make_float2(k00[i].x - t.x, k00[i].y - t.y);
            buf[SW(d4r6(l))] = cmul(cf[i], ar);       // scatter for radix-4 DIT
        }
    }
    __syncthreads();

    // ---- P2: ifft4096 (6 radix-4 DIT stages) -> K*4096 natural ----
    #pragma unroll 1
    for (int q = 1; q <= 1024; q *= 4) r4_dit_inv<2>(buf, tid, q);

    // ---- P3: pack z = u + i*K, zero-pad ----
    {
        float kv[8], uval[8];
        #pragma unroll
        for (int i = 0; i < 8; ++i) {
            int l = i*NT + tid;
            kv[i]   = buf[SW(l)].x * (1.0f/4096.0f);
            uval[i] = u[h*4096 + l];
        }
        __syncthreads();
        #pragma unroll
        for (int i = 0; i < 8; ++i) {
            int l = i*NT + tid;
            buf[SW(l)]        = make_float2(uval[i], kv[i]);
            buf[SW(l+4096)]   = make_float2(0.0f, 0.0f);
        }
    }
    __syncthreads();

    // ---- P4: forward fft8192 = r2 DIF (m=8192) + 6 radix-4 DIF stages per half ----
    {
        const float fm = -6.2831853072f / 8192.0f;
        float sb, cb; __sincosf(fm*(float)tid, &sb, &cb);
        float ss, cs; __sincosf(fm*512.0f, &ss, &cs);
        float2 cur = make_float2(cb, sb);
        const float2 stp = make_float2(cs, ss);
        #pragma unroll 1
        for (int i = 0; i < 8; ++i) {
            int j = i*NT + tid;
            int a0 = SW(j), a1 = SW(j+4096);
            float2 a = buf[a0], c = buf[a1];
            buf[a0] = cadd(a,c);
            buf[a1] = cmul(csub(a,c), cur);   // * W_8192^{-j}
            cur = cmul(cur, stp);
        }
        __syncthreads();
    }
    #pragma unroll 1
    for (int q = 1024; q >= 1; q >>= 2) r4_dif_fwd<4>(buf, tid, q);

    // ---- P5: unpack + multiply + half-size-inverse pack ----
    // Z[k] lives at (k&1)*4096 + d4r6(k>>1).
    {
        const float fm = 6.2831853072f / 8192.0f;   // W = e^{+2pi i/8192}
        float2 v[8];
        #pragma unroll 1
        for (int i = 0; i < 8; ++i) {
            int r  = i*NT + tid;                   // 0..4095
            float sw_, cw_; __sincosf(fm*(float)r, &sw_, &cw_);
            float2 cur = make_float2(cw_, sw_);
            int k1 = r,        k1c = (8192 - r) & 8191;
            int k2 = r + 4096, k2c = 4096 - r;
            float2 za = buf[SW(((k1 &1)<<12) + d4r6(k1 >>1))];
            float2 zb = buf[SW(((k1c&1)<<12) + d4r6(k1c>>1))];
            float2 zc = buf[SW(((k2 &1)<<12) + d4r6(k2 >>1))];
            float2 zd = buf[SW(((k2c&1)<<12) + d4r6(k2c>>1))];
            // Y(k) from (Z[k], Z[-k]):  U = (Z+conj(Z-))/2, Kd = (Z-conj(Z-))*(-i/2), Y = U*Kd
            float2 U1 = make_float2(0.5f*(za.x+zb.x), 0.5f*(za.y-zb.y));
            float2 V1 = make_float2(za.x-zb.x, za.y+zb.y);
            float2 K1 = make_float2(0.5f*V1.y, -0.5f*V1.x);
            float2 Yr = cmul(U1, K1);                               // Y[r]
            float2 U2 = make_float2(0.5f*(zc.x+zd.x), 0.5f*(zc.y-zd.y));
            float2 V2 = make_float2(zc.x-zd.x, zc.y+zd.y);
            float2 K2 = make_float2(0.5f*V2.y, -0.5f*V2.x);
            float2 Ys = cmul(U2, K2);                               // Y[r+4096]
            float2 A  = cadd(Yr, Ys);
            float2 Bv = cmul(cur, csub(Yr, Ys));
            v[i] = make_float2(A.x - Bv.y, A.y + Bv.x);             // A + i*W^r*(Yr-Ys)
        }
        __syncthreads();   // all reads done before any scatter write
        #pragma unroll
        for (int i = 0; i < 8; ++i) {
            int r = i*NT + tid;
            buf[SW(d4r6(r))] = v[i];
        }
        __syncthreads();
    }

    // ---- P6: ifft4096 (6 radix-4 DIT stages) -> p[n] = y[2n] + i*y[2n+1] ----
    #pragma unroll 1
    for (int q = 1; q <= 1024; q *= 4) r4_dit_inv<2>(buf, tid, q);

    // ---- P7: epilogue, float2 loads/stores ----
    {
        const float Dh = Din[h];
        const float sc = 1.0f / 8192.0f;
        const float2* u2   = (const float2*)(u + h*4096);
        float2*       out2 = (float2*)(out + h*4096);
        #pragma unroll
        for (int i = 0; i < 4; ++i) {
            int n = i*NT + tid;                   // 0..2047 -> outputs 2n, 2n+1
            float2 p  = buf[SW(n)];
            float2 uu = u2[n];
            out2[n] = make_float2(p.x*sc + Dh*uu.x, p.y*sc + Dh*uu.y);
        }
    }
}

extern "C" void kernel_launch(void* const* d_in, const int* in_sizes, int n_in,
                              void* d_out, int out_size, void* d_ws, size_t ws_size,
                              hipStream_t stream)
{
    const float* u       = (const float*)d_in[0];
    const float* Lre     = (const float*)d_in[1];
    const float* Lim     = (const float*)d_in[2];
    const float* Pre     = (const float*)d_in[3];
    const float* Pim     = (const float*)d_in[4];
    const float* Bre     = (const float*)d_in[5];
    const float* Bim     = (const float*)d_in[6];
    const float* Cin     = (const float*)d_in[7];
    const float* Din     = (const float*)d_in[8];
    const float* logstep = (const float*)d_in[9];
    float* out = (float*)d_out;
    const int H = in_sizes[8];  // D is [H,1]
    hipLaunchKernelGGL(s4_fused, dim3(H), dim3(NT), 0, stream,
                       u, Lre, Lim, Pre, Pim, Bre, Bim, Cin, Din, logstep, out);
}

// Round 4
// 176.298 us; speedup vs baseline: 1.5451x; 1.2271x over previous
//
#include <hip/hip_runtime.h>
#include <math.h>

#define NT 512   // threads per block; 512 blocks (one per channel h)

// Packed f32 pair: LLVM lowers arithmetic on this to v_pk_*_f32 (VOP3P) on gfx950.
typedef float v2 __attribute__((ext_vector_type(2)));

__device__ __forceinline__ v2 vrot(v2 a){ return (v2){-a.y, a.x}; }            // i*a
__device__ __forceinline__ v2 vconj(v2 a){ return (v2){a.x, -a.y}; }
__device__ __forceinline__ v2 vcmul(v2 a, v2 b){ return a.x*b + a.y*vrot(b); } // complex mul: 2 pk_fma
__device__ __forceinline__ v2 vfma1(float s, v2 v, v2 acc){                    // acc + s*v: 1 pk_fma
    return (v2){ __builtin_fmaf(s, v.x, acc.x), __builtin_fmaf(s, v.y, acc.y) };
}

// XOR bank swizzle: float2 elements -> bank = (2e)%32 depends on e mod 16.
__device__ __forceinline__ int SW(int e){ return e ^ (((e>>5) ^ (e>>9)) & 15); }

// base-4 digit reversal of a 12-bit index
__device__ __forceinline__ int d4r6(int x){
    int r = (int)(__builtin_bitreverse32((unsigned)x) >> 20);
    return ((r & 0x555) << 1) | ((r >> 1) & 0x555);
}

// ---- radix-4 DIT stage, inverse (sigma=+1). In-place on buf (swizzled addressing).
template<int NB>
__device__ __forceinline__ void r4_dit_inv(v2* buf, int tid, int q) {
    const float fm = 6.2831853072f / (float)(4*q);
    int j0 = tid & (q-1);
    float sb, cb; __sincosf(fm*(float)j0, &sb, &cb);
    v2 W1a = (v2){cb, sb}, W1b = W1a;
    if (q == 1024) { float ss, cs; __sincosf(fm*512.0f, &ss, &cs); W1b = vcmul(W1a, (v2){cs, ss}); }
    v2 W2a = vcmul(W1a,W1a), W3a = vcmul(W2a,W1a);
    v2 W2b = vcmul(W1b,W1b), W3b = vcmul(W2b,W1b);
    #pragma unroll
    for (int i = 0; i < NB; ++i) {
        int b = i*NT + tid;
        int j = b & (q-1);
        int e0 = 4*b - 3*j;           // block base + j
        int a0 = SW(e0), a1 = SW(e0+q), a2 = SW(e0+2*q), a3 = SW(e0+3*q);
        v2 x0 = buf[a0], x1 = buf[a1], x2 = buf[a2], x3 = buf[a3];
        v2 W1 = (i&1)?W1b:W1a, W2 = (i&1)?W2b:W2a, W3 = (i&1)?W3b:W3a;
        v2 t1 = vcmul(x1,W1), t2 = vcmul(x2,W2), t3 = vcmul(x3,W3);
        v2 E0 = x0 + t2, E1 = t1 + t3;
        v2 O0 = x0 - t2, O1 = t1 - t3;
        v2 rO1 = vrot(O1);
        buf[a0] = E0 + E1;
        buf[a2] = E0 - E1;
        buf[a1] = O0 + rO1;   // O0 + i*O1
        buf[a3] = O0 - rO1;   // O0 - i*O1
    }
    __syncthreads();
}

// ---- radix-4 DIF stage, forward (sigma=-1): butterfly then twiddle.
template<int NB>
__device__ __forceinline__ void r4_dif_fwd(v2* buf, int tid, int q) {
    const float fm = -6.2831853072f / (float)(4*q);
    int j0 = tid & (q-1);
    float sb, cb; __sincosf(fm*(float)j0, &sb, &cb);
    v2 W1a = (v2){cb, sb}, W1b = W1a;
    if (q == 1024) { float ss, cs; __sincosf(fm*512.0f, &ss, &cs); W1b = vcmul(W1a, (v2){cs, ss}); }
    v2 W2a = vcmul(W1a,W1a), W3a = vcmul(W2a,W1a);
    v2 W2b = vcmul(W1b,W1b), W3b = vcmul(W2b,W1b);
    #pragma unroll
    for (int i = 0; i < NB; ++i) {
        int b = i*NT + tid;
        int j = b & (q-1);
        int e0 = 4*b - 3*j;
        int a0 = SW(e0), a1 = SW(e0+q), a2 = SW(e0+2*q), a3 = SW(e0+3*q);
        v2 x0 = buf[a0], x1 = buf[a1], x2 = buf[a2], x3 = buf[a3];
        v2 W1 = (i&1)?W1b:W1a, W2 = (i&1)?W2b:W2a, W3 = (i&1)?W3b:W3a;
        v2 E0 = x0 + x2, E1 = x1 + x3;
        v2 O0 = x0 - x2, O1 = x1 - x3;
        v2 rO1 = vrot(O1);
        buf[a0] = E0 + E1;
        buf[a1] = vcmul(O0 - rO1, W1);   // O0 - i*O1
        buf[a2] = vcmul(E0 - E1, W2);
        buf[a3] = vcmul(O0 + rO1, W3);   // O0 + i*O1
    }
    __syncthreads();
}

// Fused S4 layer, one block per channel h. Phases as in R1/R2.
__global__ void __launch_bounds__(NT, 2)
s4_fused(const float* __restrict__ u,
         const float* __restrict__ Lre, const float* __restrict__ Lim,
         const float* __restrict__ Pre, const float* __restrict__ Pim,
         const float* __restrict__ Bre, const float* __restrict__ Bim,
         const float* __restrict__ Cin, const float* __restrict__ Din,
         const float* __restrict__ logstep,
         float* __restrict__ out)
{
    __shared__ v2 buf[8192];   // 64 KB -> 2 blocks/CU
    const int tid = threadIdx.x;
    const int h = blockIdx.x;

    // ---- P0: params in upper half (raw addressing; dead after P1) ----
    v2* par = buf + 4096;      // [0..63]=Lam, +64=w00, +128=w01, +192=w10, +256=w11(real)
    if (tid < 64) {
        const int n = tid;
        float lre = fminf(Lre[h*64+n], -1e-4f);
        float lim = Lim[h*64+n];
        par[n] = (v2){lre, lim};
        float pr = Pre[h*64+n], pi = Pim[h*64+n];
        float br = Bre[h*64+n], bi = Bim[h*64+n];
        float cr = Cin[h*128+2*n], ci = Cin[h*128+2*n+1];
        v2 cc = (v2){cr, -ci};                    // conj(C)
        par[64+n]  = vcmul(cc, (v2){br, bi});     // w00 = conj(C)*B
        par[128+n] = vcmul(cc, (v2){pr, pi});     // w01 = conj(C)*P
        v2 pc = (v2){pr, -pi};                    // conj(P)
        par[192+n] = vcmul(pc, (v2){br, bi});     // w10 = conj(P)*B
        par[256+n] = (v2){pr*pr + pi*pi, 0.0f};   // w11 = |P|^2 (real!)
    }
    __syncthreads();

    const float step = expf(logstep[h]);
    const float tos  = 2.0f / step;

    // ---- P1: Cauchy kernel (two half-passes of 4 l's) ----
    #pragma unroll 1
    for (int hp = 0; hp < 2; ++hp) {
        v2 g[4], cf[4], k00[4], k01[4], k10[4], k11[4];
        const int lbase = hp*(4*NT);
        #pragma unroll
        for (int i = 0; i < 4; ++i) {
            int l = lbase + i*NT + tid;
            // mimic reference's f32 angle; sin/cos rounded from double (critical near l=2048)
            float ang = -6.2831855f * ((float)l * (1.0f/4096.0f));
            double ds, dc;
            sincos((double)ang, &ds, &dc);
            float Omx = (float)dc, Omy = (float)ds;
            float nx = 1.0f-Omx, ny = -Omy;
            float dx = 1.0f+Omx, dy =  Omy;
            float dinv = 1.0f/(dx*dx + dy*dy);
            g[i]  = (v2){tos*((nx*dx+ny*dy)*dinv), tos*((ny*dx-nx*dy)*dinv)};
            cf[i] = (v2){2.0f*dx*dinv, -2.0f*dy*dinv};
            k00[i]=(v2)(0.0f); k01[i]=(v2)(0.0f); k10[i]=(v2)(0.0f); k11[i]=(v2)(0.0f);
        }
        #pragma unroll 1
        for (int n = 0; n < 64; ++n) {
            v2 lam = par[n];
            v2 w00 = par[64+n], w01 = par[128+n], w10 = par[192+n];
            float w11r = par[256+n].x;
            #pragma unroll
            for (int i = 0; i < 4; ++i) {
                v2 d = g[i] - lam;                               // 1 pk
                float inv = __builtin_amdgcn_rcpf(d.x*d.x + d.y*d.y);
                v2 p  = d * inv;                                 // 1 pk (splat)
                v2 cp = (v2){p.x, -p.y};                         // 1/(g-lam)    (neg folds)
                v2 rp = (v2){p.y,  p.x};                         // swap (op_sel folds)
                k00[i] = vfma1(w00.y, rp, vfma1(w00.x, cp, k00[i]));  // += w00/(g-lam)
                k01[i] = vfma1(w01.y, rp, vfma1(w01.x, cp, k01[i]));
                k10[i] = vfma1(w10.y, rp, vfma1(w10.x, cp, k10[i]));
                k11[i] = vfma1(w11r,  cp, k11[i]);                    // w11 real
            }
        }
        #pragma unroll
        for (int i = 0; i < 4; ++i) {
            int l = lbase + i*NT + tid;
            v2 opk = (v2){1.0f + k11[i].x, k11[i].y};
            float iv = 1.0f/(opk.x*opk.x + opk.y*opk.y);
            v2 r11 = vconj(opk) * iv;                    // 1/(1+k11)
            v2 t  = vcmul(vcmul(k01[i], r11), k10[i]);
            buf[SW(d4r6(l))] = vcmul(cf[i], k00[i] - t); // scatter for radix-4 DIT
        }
    }
    __syncthreads();

    // ---- P2: ifft4096 (6 radix-4 DIT stages) -> K*4096 natural ----
    #pragma unroll 1
    for (int q = 1; q <= 1024; q *= 4) r4_dit_inv<2>(buf, tid, q);

    // ---- P3: pack z = u + i*K, zero-pad ----
    {
        float kv[8], uval[8];
        #pragma unroll
        for (int i = 0; i < 8; ++i) {
            int l = i*NT + tid;
            kv[i]   = buf[SW(l)].x * (1.0f/4096.0f);
            uval[i] = u[h*4096 + l];
        }
        __syncthreads();
        #pragma unroll
        for (int i = 0; i < 8; ++i) {
            int l = i*NT + tid;
            buf[SW(l)]      = (v2){uval[i], kv[i]};
            buf[SW(l+4096)] = (v2)(0.0f);
        }
    }
    __syncthreads();

    // ---- P4: forward fft8192 = r2 DIF (m=8192) + 6 radix-4 DIF stages per half ----
    {
        const float fm = -6.2831853072f / 8192.0f;
        float sb, cb; __sincosf(fm*(float)tid, &sb, &cb);
        float ss, cs; __sincosf(fm*512.0f, &ss, &cs);
        v2 cur = (v2){cb, sb};
        const v2 stp = (v2){cs, ss};
        #pragma unroll 1
        for (int i = 0; i < 8; ++i) {
            int j = i*NT + tid;
            int a0 = SW(j), a1 = SW(j+4096);
            v2 a = buf[a0], c = buf[a1];
            buf[a0] = a + c;
            buf[a1] = vcmul(a - c, cur);   // * W_8192^{-j}
            cur = vcmul(cur, stp);
        }
        __syncthreads();
    }
    #pragma unroll 1
    for (int q = 1024; q >= 1; q >>= 2) r4_dif_fwd<4>(buf, tid, q);

    // ---- P5: unpack + multiply + half-size-inverse pack ----
    // Z[k] lives at (k&1)*4096 + d4r6(k>>1).
    {
        const float fm = 6.2831853072f / 8192.0f;   // W = e^{+2pi i/8192}
        v2 v[8];
        #pragma unroll 1
        for (int i = 0; i < 8; ++i) {
            int r  = i*NT + tid;                   // 0..4095
            float sw_, cw_; __sincosf(fm*(float)r, &sw_, &cw_);
            v2 cur = (v2){cw_, sw_};
            int k1 = r,        k1c = (8192 - r) & 8191;
            int k2 = r + 4096, k2c = 4096 - r;
            v2 za = buf[SW(((k1 &1)<<12) + d4r6(k1 >>1))];
            v2 zb = buf[SW(((k1c&1)<<12) + d4r6(k1c>>1))];
            v2 zc = buf[SW(((k2 &1)<<12) + d4r6(k2 >>1))];
            v2 zd = buf[SW(((k2c&1)<<12) + d4r6(k2c>>1))];
            // U = (Z + conj(Z[-k]))/2, Kd = (Z - conj(Z[-k]))*(-i/2), Y = U*Kd
            v2 U1 = 0.5f*(za + vconj(zb));
            v2 K1 = -0.5f*vrot(za - vconj(zb));
            v2 Yr = vcmul(U1, K1);                               // Y[r]
            v2 U2 = 0.5f*(zc + vconj(zd));
            v2 K2 = -0.5f*vrot(zc - vconj(zd));
            v2 Ys = vcmul(U2, K2);                               // Y[r+4096]
            v[i] = (Yr + Ys) + vrot(vcmul(cur, Yr - Ys));        // A + i*W^r*(Yr-Ys)
        }
        __syncthreads();   // all reads done before any scatter write
        #pragma unroll
        for (int i = 0; i < 8; ++i) {
            int r = i*NT + tid;
            buf[SW(d4r6(r))] = v[i];
        }
        __syncthreads();
    }

    // ---- P6: ifft4096 (6 radix-4 DIT stages) -> p[n] = y[2n] + i*y[2n+1] ----
    #pragma unroll 1
    for (int q = 1; q <= 1024; q *= 4) r4_dit_inv<2>(buf, tid, q);

    // ---- P7: epilogue, float2 loads/stores ----
    {
        const float Dh = Din[h];
        const float sc = 1.0f / 8192.0f;
        const v2* u2 = (const v2*)(u + h*4096);
        v2*     out2 = (v2*)(out + h*4096);
        #pragma unroll
        for (int i = 0; i < 4; ++i) {
            int n = i*NT + tid;                   // 0..2047 -> outputs 2n, 2n+1
            v2 p  = buf[SW(n)];
            v2 uu = u2[n];
            out2[n] = sc*p + Dh*uu;
        }
    }
}

extern "C" void kernel_launch(void* const* d_in, const int* in_sizes, int n_in,
                              void* d_out, int out_size, void* d_ws, size_t ws_size,
                              hipStream_t stream)
{
    const float* u       = (const float*)d_in[0];
    const float* Lre     = (const float*)d_in[1];
    const float* Lim     = (const float*)d_in[2];
    const float* Pre     = (const float*)d_in[3];
    const float* Pim     = (const float*)d_in[4];
    const float* Bre     = (const float*)d_in[5];
    const float* Bim     = (const float*)d_in[6];
    const float* Cin     = (const float*)d_in[7];
    const float* Din     = (const float*)d_in[8];
    const float* logstep = (const float*)d_in[9];
    float* out = (float*)d_out;
    const int H = in_sizes[8];  // D is [H,1]
    hipLaunchKernelGGL(s4_fused, dim3(H), dim3(NT), 0, stream,
                       u, Lre, Lim, Pre, Pim, Bre, Bim, Cin, Din, logstep, out);
}